// Round 15
// baseline (816.540 us; speedup 1.0000x reference)
//
#include <hip/hip_runtime.h>
#include <cstdint>
#include <cstddef>

#define NN 32
#define NODE_ELEMS 1605632  // 8*56*56*64 elements per slot (NHWC); bf16 storage

typedef unsigned __int128 u128;

// ---------------- host: replicate np.random.default_rng(0).random((32,32)) < 0.25 ----
static void compute_adj(bool adj[NN][NN]) {
  uint32_t pool[4];
  uint32_t hc = 0x43b0d7e5u;
  auto hashmix = [&hc](uint32_t v) -> uint32_t {
    v ^= hc; hc *= 0x931e8875u; v *= hc; v ^= v >> 16; return v;
  };
  auto mix = [](uint32_t x, uint32_t y) -> uint32_t {
    uint32_t r = x * 0xca01f9ddu - y * 0x4973f715u; r ^= r >> 16; return r;
  };
  for (int i = 0; i < 4; i++) pool[i] = hashmix(0u);
  for (int s = 0; s < 4; s++)
    for (int d = 0; d < 4; d++)
      if (s != d) pool[d] = mix(pool[d], hashmix(pool[s]));
  uint32_t hb = 0x8b51f9ddu;
  uint32_t w[8];
  for (int k = 0; k < 8; k++) {
    uint32_t v = pool[k & 3];
    v ^= hb; hb *= 0x58f38dedu; v *= hb; v ^= v >> 16;
    w[k] = v;
  }
  uint64_t s64[4];
  for (int j = 0; j < 4; j++) s64[j] = (uint64_t)w[2 * j] | ((uint64_t)w[2 * j + 1] << 32);
  u128 initstate = ((u128)s64[0] << 64) | s64[1];
  u128 initseq   = ((u128)s64[2] << 64) | s64[3];
  const u128 MULT = ((u128)0x2360ED051FC65DA4ULL << 64) | 0x4385DF649FCCF645ULL;
  u128 state = 0;
  u128 inc = (initseq << 1) | 1;
  state = state * MULT + inc;
  state += initstate;
  state = state * MULT + inc;
  for (int i = 0; i < NN; i++)
    for (int j = 0; j < NN; j++) {
      state = state * MULT + inc;
      uint64_t hi = (uint64_t)(state >> 64), lo = (uint64_t)state;
      unsigned rot = (unsigned)(hi >> 58);
      uint64_t xr = hi ^ lo;
      uint64_t out = (xr >> rot) | (xr << ((64u - rot) & 63u));
      double dv = (double)(out >> 11) * (1.0 / 9007199254740992.0);
      adj[i][j] = (dv < 0.25);
    }
}

// ---------------- device ----------------
struct NodeDesc {
  uint8_t node, npred, slot, flags;
  uint8_t pred_slot[31];
  uint8_t pad;
};
struct GroupArg { int n; NodeDesc d[16]; };
struct FinalArg { int nf; uint8_t slot[32]; };

__device__ __forceinline__ float bf2f_lo(unsigned int w) {
  union { unsigned int u; float f; } c; c.u = w << 16; return c.f;
}
__device__ __forceinline__ float bf2f_hi(unsigned int w) {
  union { unsigned int u; float f; } c; c.u = w & 0xFFFF0000u; return c.f;
}
__device__ __forceinline__ float bf2f(unsigned short h) {
  union { unsigned int u; float f; } c; c.u = ((unsigned int)h) << 16; return c.f;
}
__device__ __forceinline__ unsigned short f2bf(float f) {
  union { float f; unsigned int u; } c; c.f = f;
  unsigned int u = c.u + 0x7FFFu + ((c.u >> 16) & 1u);  // RNE
  return (unsigned short)(u >> 16);
}

// Workspace slots are bf16 NHWC: elem(b,y,x,c) = ((b*56+y)*56+x)*64 + c.
// Math fp32; inter-node storage bf16; pw weights staged in LDS as bf16.
// XCD mapping: chunk (node, image b) pinned to XCD (node+b)&7, tile fastest.
// R15: 256-thread blocks on 8x4 tiles (was 512-thread / 8x8). R12-R14 showed
// the heavy dispatch pinned at ~388 us with all pipes <15% busy regardless of
// LDS/MLP/L2-order -- structural stall. Smaller blocks: barrier scope 4 waves
// (was 8), LDS 23.7 KB -> 6 blocks/CU resident (was <=4), 2x blocks/launch
// for phase interleaving. Cost: halo redundancy 1.56x -> 1.875x.
__global__ __launch_bounds__(256) void node_kernel(
    GroupArg g,
    const float* __restrict__ x,
    const float* __restrict__ dwall,
    const float* __restrict__ pwall,
    const float* __restrict__ gmall,
    const float* __restrict__ btall,
    const float* __restrict__ mnall,
    const float* __restrict__ vrall,
    const float* __restrict__ aggw,
    unsigned short* __restrict__ wsb)   // bf16 slots
{
  __shared__ float smem[3840];                       // halo [60 pos][64 c] / t [32 pos][64 c]
  __shared__ __align__(16) unsigned short pwb[4096]; // swizzled pw weights (bf16)
  __shared__ float wlds[32];

  const int lin = blockIdx.x;
  const int xcd = lin & 7;
  const int m = lin >> 3;
  const int k = m / 98;         // node index within group (slow)
  const int j = m - k * 98;     // tile within image [0,98) (fast -> L2 locality)
  const NodeDesc nd = g.d[k];
  const int node = nd.node;
  const int b = (xcd - node) & 7;   // image pinned so (node+b)%8 == xcd
  const int t = threadIdx.x;
  const int ty = (j / 7) * 4;       // 14 y-tiles of 4 rows
  const int tx = (j % 7) * 8;       // 7 x-tiles of 8 cols

  // stage pw weights (bf16) quad-swizzled: (o,c) -> o*64 + (((c>>2)^((o>>2)&15))<<2)|(c&3)
  {
    const float* pwn = pwall + node * 4096;
    #pragma unroll
    for (int i = 0; i < 16; i++) {
      int gidx = t + 256 * i;
      int o = gidx >> 6, cc = gidx & 63;
      pwb[o * 64 + ((((cc >> 2) ^ ((o >> 2) & 15)) << 2) | (cc & 3))] = f2bf(pwn[gidx]);
    }
  }

  int dwc, pbase;   // depthwise ownership: channel + first of 8 positions
  if (nd.npred == 0) { dwc = t >> 2; pbase = (t & 3) * 8; }   // NCHW x gather layout
  else               { dwc = t & 63; pbase = (t >> 6) * 8; }  // NHWC halo layout

  const float* k9 = dwall + (node * 64 + dwc) * 9;
  float kk[9];
  #pragma unroll
  for (int q = 0; q < 9; q++) kk[q] = k9[q];

  float tv[8];

  if (nd.npred == 0) {
    // input node: depthwise stride-2 over relu(x), x is NCHW [8][64][112][112] fp32
    const float* xb = x + (size_t)(b * 64 + dwc) * 12544;
    #pragma unroll
    for (int jj = 0; jj < 8; jj++) {
      int p = pbase + jj;
      int oy = ty + (p >> 3), ox = tx + (p & 7);
      int iy0 = oy * 2 - 1, ix0 = ox * 2 - 1;
      float s = 0.f;
      #pragma unroll
      for (int dy = 0; dy < 3; dy++) {
        int iy = iy0 + dy;
        if ((unsigned)iy >= 112u) continue;
        const float* row = xb + iy * 112;
        #pragma unroll
        for (int dx = 0; dx < 3; dx++) {
          int ix = ix0 + dx;
          if ((unsigned)ix >= 112u) continue;
          s += fmaxf(row[ix], 0.f) * kk[dy * 3 + dx];
        }
      }
      tv[jj] = s;
    }
    __syncthreads();  // match else-branch barrier count (wlds)
    __syncthreads();  // (halo build)
    __syncthreads();  // (halo consume)
  } else {
    // sigmoid weights only for >=2 preds (single pred = pass-through)
    if (t < nd.npred) {
      float wv = 1.f / (1.f + expf(-aggw[node * 32 + t]));
      wlds[t] = (nd.npred == 1) ? 1.0f : wv;
    }
    __syncthreads();
    const int np = nd.npred;
    // aggregate + relu into fp32 NHWC halo from bf16 slots.
    // halo = 6 rows x 10 cols x 64 ch = 480 units of 8 ch (16 B);
    // thread owns unit t and 256+t (t<224); preds in batches of 4 ->
    // 8 independent loads in flight per thread.
    {
      float sa[2][8];
      int off[2];
      bool inb[2];
      #pragma unroll
      for (int u = 0; u < 2; u++) {
        int idx = t + u * 256;
        bool valid = (u == 0) || (t < 224);
        int pos = idx >> 3, q8 = idx & 7;
        int hy = pos / 10, hx = pos - hy * 10;
        int gy = ty + hy - 1, gx = tx + hx - 1;
        inb[u] = valid && ((unsigned)gy < 56u) && ((unsigned)gx < 56u);
        off[u] = ((b * 56 + gy) * 56 + gx) * 64 + q8 * 8;
        #pragma unroll
        for (int q = 0; q < 8; q++) sa[u][q] = 0.f;
      }
      for (int p0 = 0; p0 < np; p0 += 4) {
        uint4 v[4][2];
        #pragma unroll
        for (int pp = 0; pp < 4; pp++) {
          if (p0 + pp < np) {
            const unsigned short* pb = wsb + (size_t)nd.pred_slot[p0 + pp] * NODE_ELEMS;
            #pragma unroll
            for (int u = 0; u < 2; u++)
              if (inb[u]) v[pp][u] = *(const uint4*)(pb + off[u]);
          }
        }
        #pragma unroll
        for (int pp = 0; pp < 4; pp++) {
          if (p0 + pp < np) {
            float wv = wlds[p0 + pp];
            #pragma unroll
            for (int u = 0; u < 2; u++) {
              if (inb[u]) {
                sa[u][0] = fmaf(wv, bf2f_lo(v[pp][u].x), sa[u][0]);
                sa[u][1] = fmaf(wv, bf2f_hi(v[pp][u].x), sa[u][1]);
                sa[u][2] = fmaf(wv, bf2f_lo(v[pp][u].y), sa[u][2]);
                sa[u][3] = fmaf(wv, bf2f_hi(v[pp][u].y), sa[u][3]);
                sa[u][4] = fmaf(wv, bf2f_lo(v[pp][u].z), sa[u][4]);
                sa[u][5] = fmaf(wv, bf2f_hi(v[pp][u].z), sa[u][5]);
                sa[u][6] = fmaf(wv, bf2f_lo(v[pp][u].w), sa[u][6]);
                sa[u][7] = fmaf(wv, bf2f_hi(v[pp][u].w), sa[u][7]);
              }
            }
          }
        }
      }
      #pragma unroll
      for (int u = 0; u < 2; u++) {
        int idx = t + u * 256;
        if ((u == 0) || (t < 224)) {
          float4 s0 = make_float4(fmaxf(sa[u][0], 0.f), fmaxf(sa[u][1], 0.f),
                                  fmaxf(sa[u][2], 0.f), fmaxf(sa[u][3], 0.f));
          float4 s1 = make_float4(fmaxf(sa[u][4], 0.f), fmaxf(sa[u][5], 0.f),
                                  fmaxf(sa[u][6], 0.f), fmaxf(sa[u][7], 0.f));
          *(float4*)&smem[idx * 8] = s0;
          *(float4*)&smem[idx * 8 + 4] = s1;
        }
      }
    }
    __syncthreads();
    // depthwise 3x3 from NHWC halo: lane = channel -> conflict-free
    #pragma unroll
    for (int jj = 0; jj < 8; jj++) {
      int p = pbase + jj;
      int py = p >> 3, px = p & 7;
      const float* r0 = smem + (py * 10 + px) * 64 + dwc;
      tv[jj] = r0[0]    * kk[0] + r0[64]   * kk[1] + r0[128]  * kk[2]
             + r0[640]  * kk[3] + r0[704]  * kk[4] + r0[768]  * kk[5]
             + r0[1280] * kk[6] + r0[1344] * kk[7] + r0[1408] * kk[8];
    }
    __syncthreads();  // halo reads done; smem re-purposed as t matrix
  }

  // t matrix t[p][c] (32 pos) quad-swizzled: quad' = (c>>2) ^ ((p>>2)&15)
  #pragma unroll
  for (int jj = 0; jj < 8; jj++) {
    int p = pbase + jj;
    smem[p * 64 + (((((dwc >> 2) ^ ((p >> 2) & 15))) << 2) | (dwc & 3))] = tv[jj];
  }
  __syncthreads();

  // pointwise 64x64 over 32 positions: 4 out-channels x 2 positions per thread
  // A operand from bf16 LDS (b64 reads + convert), B from fp32 LDS (b128)
  const int oq = t & 15;          // out-channel quad selector
  const int pgrp = t >> 4;        // position pair selector [0,16)
  const int o0 = oq << 2;
  const int p0 = pgrp << 1;
  const int bswz = (pgrp >> 1) & 15;   // (p>>2) for both p0 and p0+1
  float acc[2][4] = {};           // [pj][oi]
  #pragma unroll 4
  for (int k4 = 0; k4 < 16; k4++) {
    float A[4][4];
    float4 B[2];
    #pragma unroll
    for (int oi = 0; oi < 4; oi++) {
      const uint2 av = *(const uint2*)&pwb[(o0 + oi) * 64 + ((k4 ^ oq) << 2)];
      A[oi][0] = bf2f_lo(av.x); A[oi][1] = bf2f_hi(av.x);
      A[oi][2] = bf2f_lo(av.y); A[oi][3] = bf2f_hi(av.y);
    }
    #pragma unroll
    for (int pj = 0; pj < 2; pj++)
      B[pj] = *(const float4*)&smem[(p0 + pj) * 64 + ((k4 ^ bswz) << 2)];
    #pragma unroll
    for (int pj = 0; pj < 2; pj++) {
      #pragma unroll
      for (int oi = 0; oi < 4; oi++) {
        acc[pj][oi] = fmaf(A[oi][0], B[pj].x, acc[pj][oi]);
        acc[pj][oi] = fmaf(A[oi][1], B[pj].y, acc[pj][oi]);
        acc[pj][oi] = fmaf(A[oi][2], B[pj].z, acc[pj][oi]);
        acc[pj][oi] = fmaf(A[oi][3], B[pj].w, acc[pj][oi]);
      }
    }
  }

  // BN + bf16 slot store (every node has a slot; FINAL slots persist)
  float inv[4], mn[4], bt[4];
  #pragma unroll
  for (int oi = 0; oi < 4; oi++) {
    int gi = node * 64 + o0 + oi;
    inv[oi] = gmall[gi] / sqrtf(vrall[gi] + 1e-5f);
    mn[oi] = mnall[gi];
    bt[oi] = btall[gi];
  }
  unsigned short* slotp = wsb + (size_t)nd.slot * NODE_ELEMS;
  #pragma unroll
  for (int pj = 0; pj < 2; pj++) {
    int p = p0 + pj;
    int gy = ty + (p >> 3), gx = tx + (p & 7);
    size_t base = (((size_t)(b * 56 + gy)) * 56 + gx) * 64 + o0;
    ushort4 h;
    h.x = f2bf((acc[pj][0] - mn[0]) * inv[0] + bt[0]);
    h.y = f2bf((acc[pj][1] - mn[1]) * inv[1] + bt[1]);
    h.z = f2bf((acc[pj][2] - mn[2]) * inv[2] + bt[2]);
    h.w = f2bf((acc[pj][3] - mn[3]) * inv[3] + bt[3]);
    *(ushort4*)&slotp[base] = h;
  }
}

// Mean of FINAL bf16 slots (fp32 accumulate) -> NCHW d_out. Block per (b,y) row.
__global__ __launch_bounds__(256) void finalize_kernel(
    FinalArg fa, const unsigned short* __restrict__ wsb,
    float* __restrict__ out, float inv_nf)
{
  __shared__ float lds[57 * 64];
  int by = blockIdx.x;
  int b = by / 56, y = by - b * 56;
  size_t rbase = (((size_t)b * 56 + y) * 56) * 64;  // [x][c]
  for (int i = threadIdx.x; i < 3584; i += 256) {
    float s = 0.f;
    for (int f = 0; f < fa.nf; f++)
      s += bf2f(wsb[(size_t)fa.slot[f] * NODE_ELEMS + rbase + i]);
    int xx = i >> 6, c = i & 63;
    lds[c * 57 + xx] = s * inv_nf;
  }
  __syncthreads();
  float* dst = out + (size_t)b * 64 * 3136 + y * 56;
  for (int i = threadIdx.x; i < 3584; i += 256) {
    int c = i / 56, xx = i - c * 56;
    dst[(size_t)c * 3136 + xx] = lds[c * 57 + xx];
  }
}

// ---------------- launcher ----------------
extern "C" void kernel_launch(void* const* d_in, const int* in_sizes, int n_in,
                              void* d_out, int out_size, void* d_ws, size_t ws_size,
                              hipStream_t stream) {
  (void)in_sizes; (void)n_in; (void)ws_size; (void)out_size;
  const float* x     = (const float*)d_in[0];
  const float* dw    = (const float*)d_in[1];
  const float* pw    = (const float*)d_in[2];
  const float* gamma = (const float*)d_in[3];
  const float* beta  = (const float*)d_in[4];
  const float* mean  = (const float*)d_in[5];
  const float* var   = (const float*)d_in[6];
  const float* aggw  = (const float*)d_in[7];
  unsigned short* wsb = (unsigned short*)d_ws;
  float* out = (float*)d_out;

  bool adj[NN][NN];
  compute_adj(adj);

  int npred[NN], preds[NN][NN], nsucc[NN], ispan[NN], level[NN];
  for (int j = 0; j < NN; j++) {
    npred[j] = 0;
    for (int i = 0; i < j; i++) if (adj[i][j]) preds[j][npred[j]++] = i;
  }
  for (int i = 0; i < NN; i++) {
    nsucc[i] = 0; ispan[i] = NN;
    int mx = -1;
    for (int j = i + 1; j < NN; j++) if (adj[i][j]) { nsucc[i]++; mx = j; }
    if (nsucc[i] > 0) ispan[i] = mx;
  }
  int maxlev = 0;
  for (int j = 0; j < NN; j++) {
    int lv = 0;
    for (int p = 0; p < npred[j]; p++) {
      int cand = level[preds[j][p]] + 1;
      if (cand > lv) lv = cand;
    }
    level[j] = lv;
    if (lv > maxlev) maxlev = lv;
  }
  bool isfinal[NN]; int nf = 0;
  for (int i = 0; i < NN; i++) { isfinal[i] = (ispan[i] >= NN - 1); if (isfinal[i]) nf++; }
  int lastlvl[NN];
  for (int i = 0; i < NN; i++) {
    lastlvl[i] = -1;
    for (int j = i + 1; j < NN; j++) if (adj[i][j] && level[j] > lastlvl[i]) lastlvl[i] = level[j];
  }
  // slot allocation: every node gets a slot; FINAL slots never freed.
  int slot[NN]; bool used[NN];
  for (int s = 0; s < NN; s++) used[s] = false;
  for (int L = 0; L <= maxlev; L++) {
    for (int i = 0; i < NN; i++) {
      if (level[i] != L) continue;
      int s = 0; while (used[s]) s++;
      used[s] = true; slot[i] = s;
    }
    for (int i = 0; i < NN; i++)
      if (level[i] <= L && !isfinal[i] && lastlvl[i] == L)
        used[slot[i]] = false;
  }

  float inv_nf = 1.0f / (float)nf;

  for (int L = 0; L <= maxlev; L++) {
    GroupArg g; g.n = 0;
    for (int i = 0; i < NN; i++) {
      if (level[i] != L) continue;
      NodeDesc& nd = g.d[g.n++];
      nd.node = (uint8_t)i;
      nd.npred = (uint8_t)npred[i];
      nd.slot = (uint8_t)slot[i];
      nd.flags = 0;
      for (int p = 0; p < npred[i]; p++) nd.pred_slot[p] = (uint8_t)slot[preds[i][p]];
      if (g.n == 16) {
        node_kernel<<<784 * g.n, 256, 0, stream>>>(g, x, dw, pw, gamma, beta,
                                                   mean, var, aggw, wsb);
        g.n = 0;
      }
    }
    if (g.n > 0) {
      node_kernel<<<784 * g.n, 256, 0, stream>>>(g, x, dw, pw, gamma, beta,
                                                 mean, var, aggw, wsb);
    }
  }

  FinalArg fa; fa.nf = 0;
  for (int i = 0; i < NN; i++) if (isfinal[i]) fa.slot[fa.nf++] = (uint8_t)slot[i];
  finalize_kernel<<<448, 256, 0, stream>>>(fa, wsb, out, inv_nf);
}

// Round 16
// 776.037 us; speedup vs baseline: 1.0522x; 1.0522x over previous
//
#include <hip/hip_runtime.h>
#include <cstdint>
#include <cstddef>

#define NN 32
#define NODE_ELEMS 1605632  // 8*56*56*64 elements per slot (NHWC); bf16 storage

typedef unsigned __int128 u128;

// ---------------- host: replicate np.random.default_rng(0).random((32,32)) < 0.25 ----
static void compute_adj(bool adj[NN][NN]) {
  uint32_t pool[4];
  uint32_t hc = 0x43b0d7e5u;
  auto hashmix = [&hc](uint32_t v) -> uint32_t {
    v ^= hc; hc *= 0x931e8875u; v *= hc; v ^= v >> 16; return v;
  };
  auto mix = [](uint32_t x, uint32_t y) -> uint32_t {
    uint32_t r = x * 0xca01f9ddu - y * 0x4973f715u; r ^= r >> 16; return r;
  };
  for (int i = 0; i < 4; i++) pool[i] = hashmix(0u);
  for (int s = 0; s < 4; s++)
    for (int d = 0; d < 4; d++)
      if (s != d) pool[d] = mix(pool[d], hashmix(pool[s]));
  uint32_t hb = 0x8b51f9ddu;
  uint32_t w[8];
  for (int k = 0; k < 8; k++) {
    uint32_t v = pool[k & 3];
    v ^= hb; hb *= 0x58f38dedu; v *= hb; v ^= v >> 16;
    w[k] = v;
  }
  uint64_t s64[4];
  for (int j = 0; j < 4; j++) s64[j] = (uint64_t)w[2 * j] | ((uint64_t)w[2 * j + 1] << 32);
  u128 initstate = ((u128)s64[0] << 64) | s64[1];
  u128 initseq   = ((u128)s64[2] << 64) | s64[3];
  const u128 MULT = ((u128)0x2360ED051FC65DA4ULL << 64) | 0x4385DF649FCCF645ULL;
  u128 state = 0;
  u128 inc = (initseq << 1) | 1;
  state = state * MULT + inc;
  state += initstate;
  state = state * MULT + inc;
  for (int i = 0; i < NN; i++)
    for (int j = 0; j < NN; j++) {
      state = state * MULT + inc;
      uint64_t hi = (uint64_t)(state >> 64), lo = (uint64_t)state;
      unsigned rot = (unsigned)(hi >> 58);
      uint64_t xr = hi ^ lo;
      uint64_t out = (xr >> rot) | (xr << ((64u - rot) & 63u));
      double dv = (double)(out >> 11) * (1.0 / 9007199254740992.0);
      adj[i][j] = (dv < 0.25);
    }
}

// ---------------- device ----------------
struct NodeDesc {
  uint8_t node, npred, slot, flags;
  uint8_t pred_slot[31];
  uint8_t pad;
};
struct GroupArg { int n; NodeDesc d[16]; };
struct FinalArg { int nf; uint8_t slot[32]; };

__device__ __forceinline__ float bf2f_lo(unsigned int w) {
  union { unsigned int u; float f; } c; c.u = w << 16; return c.f;
}
__device__ __forceinline__ float bf2f_hi(unsigned int w) {
  union { unsigned int u; float f; } c; c.u = w & 0xFFFF0000u; return c.f;
}
__device__ __forceinline__ float bf2f(unsigned short h) {
  union { unsigned int u; float f; } c; c.u = ((unsigned int)h) << 16; return c.f;
}
__device__ __forceinline__ unsigned short f2bf(float f) {
  union { float f; unsigned int u; } c; c.f = f;
  unsigned int u = c.u + 0x7FFFu + ((c.u >> 16) & 1u);  // RNE
  return (unsigned short)(u >> 16);
}

// Workspace slots are bf16 NHWC: elem(b,y,x,c) = ((b*56+y)*56+x)*64 + c.
// Math fp32; inter-node storage bf16; pw weights staged in LDS as bf16.
//
// XCD mapping (R16): pin IMAGE b to XCD b (b = lin&7). R11-R15 pinned
// (node+b)&7 -- but then a node's preds were written on a DIFFERENT XCD
// ((pred+b)&7), so every aggregation read was a guaranteed cross-XCD miss ->
// HBM round trip; heavy launch pinned at ~390-416 us across 4 tuning rounds
// (latency-bound: R13 314 MB vs R15 689 MB, same time). Image affinity makes
// producer and consumer the SAME XCD: per-(node,image) read set np x 0.4 MB
// ~= 3 MB fits the 4 MB L2, so last level's writes are still resident.
__global__ __launch_bounds__(512) void node_kernel(
    GroupArg g,
    const float* __restrict__ x,
    const float* __restrict__ dwall,
    const float* __restrict__ pwall,
    const float* __restrict__ gmall,
    const float* __restrict__ btall,
    const float* __restrict__ mnall,
    const float* __restrict__ vrall,
    const float* __restrict__ aggw,
    unsigned short* __restrict__ wsb)   // bf16 slots
{
  __shared__ float smem[6400];                       // halo [100 pos][64 c] / t matrix
  __shared__ __align__(16) unsigned short pwb[4096]; // swizzled pw weights (bf16)
  __shared__ float wlds[32];

  const int lin = blockIdx.x;
  const int xcd = lin & 7;
  const int m = lin >> 3;
  const int k = m / 49;         // node index within group (slow)
  const int j = m - k * 49;     // tile within image [0,49) (fast -> L2 locality)
  const NodeDesc nd = g.d[k];
  const int node = nd.node;
  const int b = xcd;            // image == XCD: producer/consumer affinity
  const int t = threadIdx.x;
  const int ty = (j / 7) * 8;
  const int tx = (j % 7) * 8;

  // stage pw weights (bf16) quad-swizzled: (o,c) -> o*64 + (((c>>2)^((o>>2)&15))<<2)|(c&3)
  {
    const float* pwn = pwall + node * 4096;
    #pragma unroll
    for (int i = 0; i < 8; i++) {
      int gidx = t + 512 * i;
      int o = gidx >> 6, cc = gidx & 63;
      pwb[o * 64 + ((((cc >> 2) ^ ((o >> 2) & 15)) << 2) | (cc & 3))] = f2bf(pwn[gidx]);
    }
  }

  int dwc, pbase;   // depthwise ownership: channel + first of 8 positions
  if (nd.npred == 0) { dwc = t >> 3; pbase = (t & 7) * 8; }   // NCHW x gather layout
  else               { dwc = t & 63; pbase = (t >> 6) * 8; }  // NHWC halo layout

  const float* k9 = dwall + (node * 64 + dwc) * 9;
  float kk[9];
  #pragma unroll
  for (int q = 0; q < 9; q++) kk[q] = k9[q];

  float tv[8];

  if (nd.npred == 0) {
    // input node: depthwise stride-2 over relu(x), x is NCHW [8][64][112][112] fp32
    const float* xb = x + (size_t)(b * 64 + dwc) * 12544;
    #pragma unroll
    for (int jj = 0; jj < 8; jj++) {
      int p = pbase + jj;
      int oy = ty + (p >> 3), ox = tx + (p & 7);
      int iy0 = oy * 2 - 1, ix0 = ox * 2 - 1;
      float s = 0.f;
      #pragma unroll
      for (int dy = 0; dy < 3; dy++) {
        int iy = iy0 + dy;
        if ((unsigned)iy >= 112u) continue;
        const float* row = xb + iy * 112;
        #pragma unroll
        for (int dx = 0; dx < 3; dx++) {
          int ix = ix0 + dx;
          if ((unsigned)ix >= 112u) continue;
          s += fmaxf(row[ix], 0.f) * kk[dy * 3 + dx];
        }
      }
      tv[jj] = s;
    }
    __syncthreads();  // match else-branch barrier count (wlds)
    __syncthreads();  // (halo build)
    __syncthreads();  // (halo consume)
  } else {
    // sigmoid weights only for >=2 preds (single pred = pass-through)
    if (t < nd.npred) {
      float wv = 1.f / (1.f + expf(-aggw[node * 32 + t]));
      wlds[t] = (nd.npred == 1) ? 1.0f : wv;
    }
    __syncthreads();
    const int np = nd.npred;
    // aggregate + relu into fp32 NHWC halo from bf16 slots.
    // 800 units of 8 channels (16 B); thread owns unit t and 512+t (t<288).
    // Preds in batches of 4 -> 8 independent loads in flight per thread.
    {
      float sa[2][8];
      int off[2];
      bool inb[2];
      #pragma unroll
      for (int u = 0; u < 2; u++) {
        int idx = t + u * 512;
        bool valid = (u == 0) || (t < 288);
        int pos = idx >> 3, q8 = idx & 7;
        int hy = pos / 10, hx = pos - hy * 10;
        int gy = ty + hy - 1, gx = tx + hx - 1;
        inb[u] = valid && ((unsigned)gy < 56u) && ((unsigned)gx < 56u);
        off[u] = ((b * 56 + gy) * 56 + gx) * 64 + q8 * 8;
        #pragma unroll
        for (int q = 0; q < 8; q++) sa[u][q] = 0.f;
      }
      for (int p0 = 0; p0 < np; p0 += 4) {
        uint4 v[4][2];
        #pragma unroll
        for (int pp = 0; pp < 4; pp++) {
          if (p0 + pp < np) {
            const unsigned short* pb = wsb + (size_t)nd.pred_slot[p0 + pp] * NODE_ELEMS;
            #pragma unroll
            for (int u = 0; u < 2; u++)
              if (inb[u]) v[pp][u] = *(const uint4*)(pb + off[u]);
          }
        }
        #pragma unroll
        for (int pp = 0; pp < 4; pp++) {
          if (p0 + pp < np) {
            float wv = wlds[p0 + pp];
            #pragma unroll
            for (int u = 0; u < 2; u++) {
              if (inb[u]) {
                sa[u][0] = fmaf(wv, bf2f_lo(v[pp][u].x), sa[u][0]);
                sa[u][1] = fmaf(wv, bf2f_hi(v[pp][u].x), sa[u][1]);
                sa[u][2] = fmaf(wv, bf2f_lo(v[pp][u].y), sa[u][2]);
                sa[u][3] = fmaf(wv, bf2f_hi(v[pp][u].y), sa[u][3]);
                sa[u][4] = fmaf(wv, bf2f_lo(v[pp][u].z), sa[u][4]);
                sa[u][5] = fmaf(wv, bf2f_hi(v[pp][u].z), sa[u][5]);
                sa[u][6] = fmaf(wv, bf2f_lo(v[pp][u].w), sa[u][6]);
                sa[u][7] = fmaf(wv, bf2f_hi(v[pp][u].w), sa[u][7]);
              }
            }
          }
        }
      }
      #pragma unroll
      for (int u = 0; u < 2; u++) {
        int idx = t + u * 512;
        if ((u == 0) || (t < 288)) {
          float4 s0 = make_float4(fmaxf(sa[u][0], 0.f), fmaxf(sa[u][1], 0.f),
                                  fmaxf(sa[u][2], 0.f), fmaxf(sa[u][3], 0.f));
          float4 s1 = make_float4(fmaxf(sa[u][4], 0.f), fmaxf(sa[u][5], 0.f),
                                  fmaxf(sa[u][6], 0.f), fmaxf(sa[u][7], 0.f));
          *(float4*)&smem[idx * 8] = s0;
          *(float4*)&smem[idx * 8 + 4] = s1;
        }
      }
    }
    __syncthreads();
    // depthwise 3x3 from NHWC halo: lane = channel -> conflict-free
    #pragma unroll
    for (int jj = 0; jj < 8; jj++) {
      int p = pbase + jj;
      int py = p >> 3, px = p & 7;
      const float* r0 = smem + (py * 10 + px) * 64 + dwc;
      tv[jj] = r0[0]    * kk[0] + r0[64]   * kk[1] + r0[128]  * kk[2]
             + r0[640]  * kk[3] + r0[704]  * kk[4] + r0[768]  * kk[5]
             + r0[1280] * kk[6] + r0[1344] * kk[7] + r0[1408] * kk[8];
    }
    __syncthreads();  // halo reads done; smem re-purposed as t matrix
  }

  // t matrix t[p][c] quad-swizzled: quad' = (c>>2) ^ ((p>>2)&15)
  #pragma unroll
  for (int jj = 0; jj < 8; jj++) {
    int p = pbase + jj;
    smem[p * 64 + (((((dwc >> 2) ^ ((p >> 2) & 15))) << 2) | (dwc & 3))] = tv[jj];
  }
  __syncthreads();

  // pointwise 64x64: 4 out-channels x 2 positions per thread (8 acc)
  // A operand from bf16 LDS (b64 reads + convert), B from fp32 LDS (b128)
  const int oq = t & 15;          // out-channel quad selector
  const int pgrp = t >> 4;        // position pair selector [0,32)
  const int o0 = oq << 2;
  const int p0 = pgrp << 1;
  const int bswz = (pgrp >> 1) & 15;   // (p>>2) for both p0 and p0+1
  float acc[2][4] = {};           // [pj][oi]
  #pragma unroll 4
  for (int k4 = 0; k4 < 16; k4++) {
    float A[4][4];
    float4 B[2];
    #pragma unroll
    for (int oi = 0; oi < 4; oi++) {
      const uint2 av = *(const uint2*)&pwb[(o0 + oi) * 64 + ((k4 ^ oq) << 2)];
      A[oi][0] = bf2f_lo(av.x); A[oi][1] = bf2f_hi(av.x);
      A[oi][2] = bf2f_lo(av.y); A[oi][3] = bf2f_hi(av.y);
    }
    #pragma unroll
    for (int pj = 0; pj < 2; pj++)
      B[pj] = *(const float4*)&smem[(p0 + pj) * 64 + ((k4 ^ bswz) << 2)];
    #pragma unroll
    for (int pj = 0; pj < 2; pj++) {
      #pragma unroll
      for (int oi = 0; oi < 4; oi++) {
        acc[pj][oi] = fmaf(A[oi][0], B[pj].x, acc[pj][oi]);
        acc[pj][oi] = fmaf(A[oi][1], B[pj].y, acc[pj][oi]);
        acc[pj][oi] = fmaf(A[oi][2], B[pj].z, acc[pj][oi]);
        acc[pj][oi] = fmaf(A[oi][3], B[pj].w, acc[pj][oi]);
      }
    }
  }

  // BN + bf16 slot store (every node has a slot; FINAL slots persist)
  float inv[4], mn[4], bt[4];
  #pragma unroll
  for (int oi = 0; oi < 4; oi++) {
    int gi = node * 64 + o0 + oi;
    inv[oi] = gmall[gi] / sqrtf(vrall[gi] + 1e-5f);
    mn[oi] = mnall[gi];
    bt[oi] = btall[gi];
  }
  unsigned short* slotp = wsb + (size_t)nd.slot * NODE_ELEMS;
  #pragma unroll
  for (int pj = 0; pj < 2; pj++) {
    int p = p0 + pj;
    int gy = ty + (p >> 3), gx = tx + (p & 7);
    size_t base = (((size_t)(b * 56 + gy)) * 56 + gx) * 64 + o0;
    ushort4 h;
    h.x = f2bf((acc[pj][0] - mn[0]) * inv[0] + bt[0]);
    h.y = f2bf((acc[pj][1] - mn[1]) * inv[1] + bt[1]);
    h.z = f2bf((acc[pj][2] - mn[2]) * inv[2] + bt[2]);
    h.w = f2bf((acc[pj][3] - mn[3]) * inv[3] + bt[3]);
    *(ushort4*)&slotp[base] = h;
  }
}

// Mean of FINAL bf16 slots (fp32 accumulate) -> NCHW d_out. Block per (b,y) row.
__global__ __launch_bounds__(256) void finalize_kernel(
    FinalArg fa, const unsigned short* __restrict__ wsb,
    float* __restrict__ out, float inv_nf)
{
  __shared__ float lds[57 * 64];
  int by = blockIdx.x;
  int b = by / 56, y = by - b * 56;
  size_t rbase = (((size_t)b * 56 + y) * 56) * 64;  // [x][c]
  for (int i = threadIdx.x; i < 3584; i += 256) {
    float s = 0.f;
    for (int f = 0; f < fa.nf; f++)
      s += bf2f(wsb[(size_t)fa.slot[f] * NODE_ELEMS + rbase + i]);
    int xx = i >> 6, c = i & 63;
    lds[c * 57 + xx] = s * inv_nf;
  }
  __syncthreads();
  float* dst = out + (size_t)b * 64 * 3136 + y * 56;
  for (int i = threadIdx.x; i < 3584; i += 256) {
    int c = i / 56, xx = i - c * 56;
    dst[(size_t)c * 3136 + xx] = lds[c * 57 + xx];
  }
}

// ---------------- launcher ----------------
extern "C" void kernel_launch(void* const* d_in, const int* in_sizes, int n_in,
                              void* d_out, int out_size, void* d_ws, size_t ws_size,
                              hipStream_t stream) {
  (void)in_sizes; (void)n_in; (void)ws_size; (void)out_size;
  const float* x     = (const float*)d_in[0];
  const float* dw    = (const float*)d_in[1];
  const float* pw    = (const float*)d_in[2];
  const float* gamma = (const float*)d_in[3];
  const float* beta  = (const float*)d_in[4];
  const float* mean  = (const float*)d_in[5];
  const float* var   = (const float*)d_in[6];
  const float* aggw  = (const float*)d_in[7];
  unsigned short* wsb = (unsigned short*)d_ws;
  float* out = (float*)d_out;

  bool adj[NN][NN];
  compute_adj(adj);

  int npred[NN], preds[NN][NN], nsucc[NN], ispan[NN], level[NN];
  for (int j = 0; j < NN; j++) {
    npred[j] = 0;
    for (int i = 0; i < j; i++) if (adj[i][j]) preds[j][npred[j]++] = i;
  }
  for (int i = 0; i < NN; i++) {
    nsucc[i] = 0; ispan[i] = NN;
    int mx = -1;
    for (int j = i + 1; j < NN; j++) if (adj[i][j]) { nsucc[i]++; mx = j; }
    if (nsucc[i] > 0) ispan[i] = mx;
  }
  int maxlev = 0;
  for (int j = 0; j < NN; j++) {
    int lv = 0;
    for (int p = 0; p < npred[j]; p++) {
      int cand = level[preds[j][p]] + 1;
      if (cand > lv) lv = cand;
    }
    level[j] = lv;
    if (lv > maxlev) maxlev = lv;
  }
  bool isfinal[NN]; int nf = 0;
  for (int i = 0; i < NN; i++) { isfinal[i] = (ispan[i] >= NN - 1); if (isfinal[i]) nf++; }
  int lastlvl[NN];
  for (int i = 0; i < NN; i++) {
    lastlvl[i] = -1;
    for (int j = i + 1; j < NN; j++) if (adj[i][j] && level[j] > lastlvl[i]) lastlvl[i] = level[j];
  }
  // slot allocation: every node gets a slot; FINAL slots never freed.
  int slot[NN]; bool used[NN];
  for (int s = 0; s < NN; s++) used[s] = false;
  for (int L = 0; L <= maxlev; L++) {
    for (int i = 0; i < NN; i++) {
      if (level[i] != L) continue;
      int s = 0; while (used[s]) s++;
      used[s] = true; slot[i] = s;
    }
    for (int i = 0; i < NN; i++)
      if (level[i] <= L && !isfinal[i] && lastlvl[i] == L)
        used[slot[i]] = false;
  }

  float inv_nf = 1.0f / (float)nf;

  for (int L = 0; L <= maxlev; L++) {
    GroupArg g; g.n = 0;
    for (int i = 0; i < NN; i++) {
      if (level[i] != L) continue;
      NodeDesc& nd = g.d[g.n++];
      nd.node = (uint8_t)i;
      nd.npred = (uint8_t)npred[i];
      nd.slot = (uint8_t)slot[i];
      nd.flags = 0;
      for (int p = 0; p < npred[i]; p++) nd.pred_slot[p] = (uint8_t)slot[preds[i][p]];
      if (g.n == 16) {
        node_kernel<<<392 * g.n, 512, 0, stream>>>(g, x, dw, pw, gamma, beta,
                                                   mean, var, aggw, wsb);
        g.n = 0;
      }
    }
    if (g.n > 0) {
      node_kernel<<<392 * g.n, 512, 0, stream>>>(g, x, dw, pw, gamma, beta,
                                                 mean, var, aggw, wsb);
    }
  }

  FinalArg fa; fa.nf = 0;
  for (int i = 0; i < NN; i++) if (isfinal[i]) fa.slot[fa.nf++] = (uint8_t)slot[i];
  finalize_kernel<<<448, 256, 0, stream>>>(fa, wsb, out, inv_nf);
}

// Round 17
// 740.535 us; speedup vs baseline: 1.1026x; 1.0479x over previous
//
#include <hip/hip_runtime.h>
#include <cstdint>
#include <cstddef>

#define NN 32
#define NODE_ELEMS 1605632  // 8*56*56*64 elements per slot (NHWC); bf16 storage

typedef unsigned __int128 u128;

// ---------------- host: replicate np.random.default_rng(0).random((32,32)) < 0.25 ----
static void compute_adj(bool adj[NN][NN]) {
  uint32_t pool[4];
  uint32_t hc = 0x43b0d7e5u;
  auto hashmix = [&hc](uint32_t v) -> uint32_t {
    v ^= hc; hc *= 0x931e8875u; v *= hc; v ^= v >> 16; return v;
  };
  auto mix = [](uint32_t x, uint32_t y) -> uint32_t {
    uint32_t r = x * 0xca01f9ddu - y * 0x4973f715u; r ^= r >> 16; return r;
  };
  for (int i = 0; i < 4; i++) pool[i] = hashmix(0u);
  for (int s = 0; s < 4; s++)
    for (int d = 0; d < 4; d++)
      if (s != d) pool[d] = mix(pool[d], hashmix(pool[s]));
  uint32_t hb = 0x8b51f9ddu;
  uint32_t w[8];
  for (int k = 0; k < 8; k++) {
    uint32_t v = pool[k & 3];
    v ^= hb; hb *= 0x58f38dedu; v *= hb; v ^= v >> 16;
    w[k] = v;
  }
  uint64_t s64[4];
  for (int j = 0; j < 4; j++) s64[j] = (uint64_t)w[2 * j] | ((uint64_t)w[2 * j + 1] << 32);
  u128 initstate = ((u128)s64[0] << 64) | s64[1];
  u128 initseq   = ((u128)s64[2] << 64) | s64[3];
  const u128 MULT = ((u128)0x2360ED051FC65DA4ULL << 64) | 0x4385DF649FCCF645ULL;
  u128 state = 0;
  u128 inc = (initseq << 1) | 1;
  state = state * MULT + inc;
  state += initstate;
  state = state * MULT + inc;
  for (int i = 0; i < NN; i++)
    for (int j = 0; j < NN; j++) {
      state = state * MULT + inc;
      uint64_t hi = (uint64_t)(state >> 64), lo = (uint64_t)state;
      unsigned rot = (unsigned)(hi >> 58);
      uint64_t xr = hi ^ lo;
      uint64_t out = (xr >> rot) | (xr << ((64u - rot) & 63u));
      double dv = (double)(out >> 11) * (1.0 / 9007199254740992.0);
      adj[i][j] = (dv < 0.25);
    }
}

// ---------------- device ----------------
struct NodeDesc {
  uint8_t node, npred, slot, flags;
  uint8_t pred_slot[31];
  uint8_t pad;
};
struct GroupArg { int n; NodeDesc d[32]; };   // one launch per LEVEL, all nodes inside
struct FinalArg { int nf; uint8_t slot[32]; };

__device__ __forceinline__ float bf2f_lo(unsigned int w) {
  union { unsigned int u; float f; } c; c.u = w << 16; return c.f;
}
__device__ __forceinline__ float bf2f_hi(unsigned int w) {
  union { unsigned int u; float f; } c; c.u = w & 0xFFFF0000u; return c.f;
}
__device__ __forceinline__ float bf2f(unsigned short h) {
  union { unsigned int u; float f; } c; c.u = ((unsigned int)h) << 16; return c.f;
}
__device__ __forceinline__ unsigned short f2bf(float f) {
  union { float f; unsigned int u; } c; c.f = f;
  unsigned int u = c.u + 0x7FFFu + ((c.u >> 16) & 1u);  // RNE
  return (unsigned short)(u >> 16);
}

// Workspace slots bf16 NHWC: elem(b,y,x,c) = ((b*56+y)*56+x)*64 + c.
// Math fp32; storage bf16. Image b pinned to XCD b (R16: FETCH 246->24.5 MB,
// producer/consumer L2 affinity confirmed).
//
// R17 STRUCTURAL CHANGE: persistent blocks per launch. R13-R16 heavy launch
// was pinned at ~385-416 us across every data-side knob while all pipes sat
// <30% busy: 6272 blocks / ~1.7 resident per CU = ~12 sequential block
// generations x ~31 us apparent lifetime vs ~3 us computable critical path
// -> per-block-generation churn, not a data pipe. Now grid = 784 blocks
// (8 img x 98 tiles, 256 thr) and the LEVEL'S NODE LOOP runs INSIDE the
// kernel; next node's pw weights stage into a double-buffered LDS bank
// during the current node's aggregation. Blocks never retire mid-launch.
__global__ __launch_bounds__(256) void level_kernel(
    GroupArg g,
    const float* __restrict__ x,
    const float* __restrict__ dwall,
    const float* __restrict__ pwall,
    const float* __restrict__ gmall,
    const float* __restrict__ btall,
    const float* __restrict__ mnall,
    const float* __restrict__ vrall,
    const float* __restrict__ aggw,
    unsigned short* __restrict__ wsb)   // bf16 slots
{
  __shared__ float smem[3840];                          // halo [6r][10c][64ch] / t [32p][64c]
  __shared__ __align__(16) unsigned short pwb[2][4096]; // double-buffered pw weights (bf16)
  __shared__ float wlds[32];

  const int b = blockIdx.x & 7;       // image == XCD
  const int m = blockIdx.x >> 3;      // tile [0,98)
  const int t = threadIdx.x;
  const int ty = (m / 7) * 4;         // 14 y-tiles of 4 rows
  const int tx = (m % 7) * 8;         // 7 x-tiles of 8 cols

  // stage node g.d[kk]'s pw weights (bf16, quad-swizzled) into pwb[bb]
  auto stage = [&](int kk, int bb) {
    const float* pwn = pwall + g.d[kk].node * 4096;
    #pragma unroll
    for (int i = 0; i < 16; i++) {
      int gidx = t + 256 * i;
      int o = gidx >> 6, cc = gidx & 63;
      pwb[bb][o * 64 + ((((cc >> 2) ^ ((o >> 2) & 15)) << 2) | (cc & 3))] = f2bf(pwn[gidx]);
    }
  };

  stage(0, 0);   // node 0's weights; visible after B1 of iteration 0

  for (int kk = 0; kk < g.n; kk++) {
    const NodeDesc nd = g.d[kk];
    const int node = nd.node;

    int dwc, pbase;
    if (nd.npred == 0) { dwc = t >> 2; pbase = (t & 3) * 8; }
    else               { dwc = t & 63; pbase = (t >> 6) * 8; }

    // aggregation weights for this node
    if (t < nd.npred) {
      float wv = 1.f / (1.f + expf(-aggw[node * 32 + t]));
      wlds[t] = (nd.npred == 1) ? 1.0f : wv;
    }
    __syncthreads();   // B1: wlds + pwb[kk&1] (staged last iter) visible; smem free

    const float* k9 = dwall + (node * 64 + dwc) * 9;
    float kk9[9];
    #pragma unroll
    for (int q = 0; q < 9; q++) kk9[q] = k9[q];

    float tv[8];

    if (nd.npred == 0) {
      // input node: depthwise stride-2 over relu(x), x NCHW [8][64][112][112]
      const float* xb = x + (size_t)(b * 64 + dwc) * 12544;
      #pragma unroll
      for (int jj = 0; jj < 8; jj++) {
        int p = pbase + jj;
        int oy = ty + (p >> 3), ox = tx + (p & 7);
        int iy0 = oy * 2 - 1, ix0 = ox * 2 - 1;
        float s = 0.f;
        #pragma unroll
        for (int dy = 0; dy < 3; dy++) {
          int iy = iy0 + dy;
          if ((unsigned)iy >= 112u) continue;
          const float* row = xb + iy * 112;
          #pragma unroll
          for (int dx = 0; dx < 3; dx++) {
            int ix = ix0 + dx;
            if ((unsigned)ix >= 112u) continue;
            s += fmaxf(row[ix], 0.f) * kk9[dy * 3 + dx];
          }
        }
        tv[jj] = s;
      }
      if (kk + 1 < g.n) stage(kk + 1, (kk + 1) & 1);
      __syncthreads();   // B2 (uniform barrier count)
    } else {
      // aggregate + relu into fp32 NHWC halo (480 units of 8 ch = 16 B)
      const int np = nd.npred;
      float sa[2][8];
      int off[2];
      bool inb[2];
      #pragma unroll
      for (int u = 0; u < 2; u++) {
        int idx = t + u * 256;
        bool valid = (u == 0) || (t < 224);
        int pos = idx >> 3, q8 = idx & 7;
        int hy = pos / 10, hx = pos - hy * 10;
        int gy = ty + hy - 1, gx = tx + hx - 1;
        inb[u] = valid && ((unsigned)gy < 56u) && ((unsigned)gx < 56u);
        off[u] = ((b * 56 + gy) * 56 + gx) * 64 + q8 * 8;
        #pragma unroll
        for (int q = 0; q < 8; q++) sa[u][q] = 0.f;
      }
      for (int p0 = 0; p0 < np; p0 += 4) {
        uint4 v[4][2];
        #pragma unroll
        for (int pp = 0; pp < 4; pp++) {
          if (p0 + pp < np) {
            const unsigned short* pb = wsb + (size_t)nd.pred_slot[p0 + pp] * NODE_ELEMS;
            #pragma unroll
            for (int u = 0; u < 2; u++)
              if (inb[u]) v[pp][u] = *(const uint4*)(pb + off[u]);
          }
        }
        #pragma unroll
        for (int pp = 0; pp < 4; pp++) {
          if (p0 + pp < np) {
            float wv = wlds[p0 + pp];
            #pragma unroll
            for (int u = 0; u < 2; u++) {
              if (inb[u]) {
                sa[u][0] = fmaf(wv, bf2f_lo(v[pp][u].x), sa[u][0]);
                sa[u][1] = fmaf(wv, bf2f_hi(v[pp][u].x), sa[u][1]);
                sa[u][2] = fmaf(wv, bf2f_lo(v[pp][u].y), sa[u][2]);
                sa[u][3] = fmaf(wv, bf2f_hi(v[pp][u].y), sa[u][3]);
                sa[u][4] = fmaf(wv, bf2f_lo(v[pp][u].z), sa[u][4]);
                sa[u][5] = fmaf(wv, bf2f_hi(v[pp][u].z), sa[u][5]);
                sa[u][6] = fmaf(wv, bf2f_lo(v[pp][u].w), sa[u][6]);
                sa[u][7] = fmaf(wv, bf2f_hi(v[pp][u].w), sa[u][7]);
              }
            }
          }
        }
      }
      #pragma unroll
      for (int u = 0; u < 2; u++) {
        int idx = t + u * 256;
        if ((u == 0) || (t < 224)) {
          float4 s0 = make_float4(fmaxf(sa[u][0], 0.f), fmaxf(sa[u][1], 0.f),
                                  fmaxf(sa[u][2], 0.f), fmaxf(sa[u][3], 0.f));
          float4 s1 = make_float4(fmaxf(sa[u][4], 0.f), fmaxf(sa[u][5], 0.f),
                                  fmaxf(sa[u][6], 0.f), fmaxf(sa[u][7], 0.f));
          *(float4*)&smem[idx * 8] = s0;
          *(float4*)&smem[idx * 8 + 4] = s1;
        }
      }
      if (kk + 1 < g.n) stage(kk + 1, (kk + 1) & 1);   // overlap next pwb with this agg
      __syncthreads();   // B2: halo ready
      // depthwise 3x3 from NHWC halo: lane = channel -> conflict-free
      #pragma unroll
      for (int jj = 0; jj < 8; jj++) {
        int p = pbase + jj;
        int py = p >> 3, px = p & 7;
        const float* r0 = smem + (py * 10 + px) * 64 + dwc;
        tv[jj] = r0[0]    * kk9[0] + r0[64]   * kk9[1] + r0[128]  * kk9[2]
               + r0[640]  * kk9[3] + r0[704]  * kk9[4] + r0[768]  * kk9[5]
               + r0[1280] * kk9[6] + r0[1344] * kk9[7] + r0[1408] * kk9[8];
      }
    }
    __syncthreads();   // B3: halo reads done; smem re-purposed as t matrix

    // t matrix t[p][c] (32 pos) quad-swizzled: quad' = (c>>2) ^ ((p>>2)&15)
    #pragma unroll
    for (int jj = 0; jj < 8; jj++) {
      int p = pbase + jj;
      smem[p * 64 + (((((dwc >> 2) ^ ((p >> 2) & 15))) << 2) | (dwc & 3))] = tv[jj];
    }
    __syncthreads();   // B4: t ready

    // pointwise 64x64 over 32 positions: 4 oc x 2 pos per thread
    const int oq = t & 15;
    const int pgrp = t >> 4;
    const int o0 = oq << 2;
    const int p0 = pgrp << 1;
    const int bswz = (pgrp >> 1) & 15;
    const unsigned short* pwc = pwb[kk & 1];
    float acc[2][4] = {};
    #pragma unroll 4
    for (int k4 = 0; k4 < 16; k4++) {
      float A[4][4];
      float4 B[2];
      #pragma unroll
      for (int oi = 0; oi < 4; oi++) {
        const uint2 av = *(const uint2*)&pwc[(o0 + oi) * 64 + ((k4 ^ oq) << 2)];
        A[oi][0] = bf2f_lo(av.x); A[oi][1] = bf2f_hi(av.x);
        A[oi][2] = bf2f_lo(av.y); A[oi][3] = bf2f_hi(av.y);
      }
      #pragma unroll
      for (int pj = 0; pj < 2; pj++)
        B[pj] = *(const float4*)&smem[(p0 + pj) * 64 + ((k4 ^ bswz) << 2)];
      #pragma unroll
      for (int pj = 0; pj < 2; pj++) {
        #pragma unroll
        for (int oi = 0; oi < 4; oi++) {
          acc[pj][oi] = fmaf(A[oi][0], B[pj].x, acc[pj][oi]);
          acc[pj][oi] = fmaf(A[oi][1], B[pj].y, acc[pj][oi]);
          acc[pj][oi] = fmaf(A[oi][2], B[pj].z, acc[pj][oi]);
          acc[pj][oi] = fmaf(A[oi][3], B[pj].w, acc[pj][oi]);
        }
      }
    }

    // BN + bf16 slot store
    float inv[4], mn[4], bt[4];
    #pragma unroll
    for (int oi = 0; oi < 4; oi++) {
      int gi = node * 64 + o0 + oi;
      inv[oi] = gmall[gi] / sqrtf(vrall[gi] + 1e-5f);
      mn[oi] = mnall[gi];
      bt[oi] = btall[gi];
    }
    unsigned short* slotp = wsb + (size_t)nd.slot * NODE_ELEMS;
    #pragma unroll
    for (int pj = 0; pj < 2; pj++) {
      int p = p0 + pj;
      int gy = ty + (p >> 3), gx = tx + (p & 7);
      size_t base = (((size_t)(b * 56 + gy)) * 56 + gx) * 64 + o0;
      ushort4 h;
      h.x = f2bf((acc[pj][0] - mn[0]) * inv[0] + bt[0]);
      h.y = f2bf((acc[pj][1] - mn[1]) * inv[1] + bt[1]);
      h.z = f2bf((acc[pj][2] - mn[2]) * inv[2] + bt[2]);
      h.w = f2bf((acc[pj][3] - mn[3]) * inv[3] + bt[3]);
      *(ushort4*)&slotp[base] = h;
    }
    __syncthreads();   // B5: smem free for next node's halo
  }
}

// Mean of FINAL bf16 slots (fp32 accumulate) -> NCHW d_out. Block per (b,y) row.
__global__ __launch_bounds__(256) void finalize_kernel(
    FinalArg fa, const unsigned short* __restrict__ wsb,
    float* __restrict__ out, float inv_nf)
{
  __shared__ float lds[57 * 64];
  int by = blockIdx.x;
  int b = by / 56, y = by - b * 56;
  size_t rbase = (((size_t)b * 56 + y) * 56) * 64;  // [x][c]
  for (int i = threadIdx.x; i < 3584; i += 256) {
    float s = 0.f;
    for (int f = 0; f < fa.nf; f++)
      s += bf2f(wsb[(size_t)fa.slot[f] * NODE_ELEMS + rbase + i]);
    int xx = i >> 6, c = i & 63;
    lds[c * 57 + xx] = s * inv_nf;
  }
  __syncthreads();
  float* dst = out + (size_t)b * 64 * 3136 + y * 56;
  for (int i = threadIdx.x; i < 3584; i += 256) {
    int c = i / 56, xx = i - c * 56;
    dst[(size_t)c * 3136 + xx] = lds[c * 57 + xx];
  }
}

// ---------------- launcher ----------------
extern "C" void kernel_launch(void* const* d_in, const int* in_sizes, int n_in,
                              void* d_out, int out_size, void* d_ws, size_t ws_size,
                              hipStream_t stream) {
  (void)in_sizes; (void)n_in; (void)ws_size; (void)out_size;
  const float* x     = (const float*)d_in[0];
  const float* dw    = (const float*)d_in[1];
  const float* pw    = (const float*)d_in[2];
  const float* gamma = (const float*)d_in[3];
  const float* beta  = (const float*)d_in[4];
  const float* mean  = (const float*)d_in[5];
  const float* var   = (const float*)d_in[6];
  const float* aggw  = (const float*)d_in[7];
  unsigned short* wsb = (unsigned short*)d_ws;
  float* out = (float*)d_out;

  bool adj[NN][NN];
  compute_adj(adj);

  int npred[NN], preds[NN][NN], nsucc[NN], ispan[NN], level[NN];
  for (int j = 0; j < NN; j++) {
    npred[j] = 0;
    for (int i = 0; i < j; i++) if (adj[i][j]) preds[j][npred[j]++] = i;
  }
  for (int i = 0; i < NN; i++) {
    nsucc[i] = 0; ispan[i] = NN;
    int mx = -1;
    for (int j = i + 1; j < NN; j++) if (adj[i][j]) { nsucc[i]++; mx = j; }
    if (nsucc[i] > 0) ispan[i] = mx;
  }
  int maxlev = 0;
  for (int j = 0; j < NN; j++) {
    int lv = 0;
    for (int p = 0; p < npred[j]; p++) {
      int cand = level[preds[j][p]] + 1;
      if (cand > lv) lv = cand;
    }
    level[j] = lv;
    if (lv > maxlev) maxlev = lv;
  }
  bool isfinal[NN]; int nf = 0;
  for (int i = 0; i < NN; i++) { isfinal[i] = (ispan[i] >= NN - 1); if (isfinal[i]) nf++; }
  int lastlvl[NN];
  for (int i = 0; i < NN; i++) {
    lastlvl[i] = -1;
    for (int j = i + 1; j < NN; j++) if (adj[i][j] && level[j] > lastlvl[i]) lastlvl[i] = level[j];
  }
  // slot allocation: every node gets a slot; FINAL slots never freed.
  int slot[NN]; bool used[NN];
  for (int s = 0; s < NN; s++) used[s] = false;
  for (int L = 0; L <= maxlev; L++) {
    for (int i = 0; i < NN; i++) {
      if (level[i] != L) continue;
      int s = 0; while (used[s]) s++;
      used[s] = true; slot[i] = s;
    }
    for (int i = 0; i < NN; i++)
      if (level[i] <= L && !isfinal[i] && lastlvl[i] == L)
        used[slot[i]] = false;
  }

  float inv_nf = 1.0f / (float)nf;

  for (int L = 0; L <= maxlev; L++) {
    GroupArg g; g.n = 0;
    for (int i = 0; i < NN; i++) {
      if (level[i] != L) continue;
      NodeDesc& nd = g.d[g.n++];
      nd.node = (uint8_t)i;
      nd.npred = (uint8_t)npred[i];
      nd.slot = (uint8_t)slot[i];
      nd.flags = 0;
      for (int p = 0; p < npred[i]; p++) nd.pred_slot[p] = (uint8_t)slot[preds[i][p]];
    }
    if (g.n > 0) {
      level_kernel<<<784, 256, 0, stream>>>(g, x, dw, pw, gamma, beta,
                                            mean, var, aggw, wsb);
    }
  }

  FinalArg fa; fa.nf = 0;
  for (int i = 0; i < NN; i++) if (isfinal[i]) fa.slot[fa.nf++] = (uint8_t)slot[i];
  finalize_kernel<<<448, 256, 0, stream>>>(fa, wsb, out, inv_nf);
}

// Round 18
// 602.957 us; speedup vs baseline: 1.3542x; 1.2282x over previous
//
#include <hip/hip_runtime.h>
#include <cstdint>
#include <cstddef>

#define NN 32
#define NODE_ELEMS 1605632  // 8*56*56*64 elements per slot (NHWC); bf16 storage

typedef unsigned __int128 u128;
typedef __attribute__((ext_vector_type(8))) short bf16x8;
typedef __attribute__((ext_vector_type(4))) float f32x4;

// ---------------- host: replicate np.random.default_rng(0).random((32,32)) < 0.25 ----
static void compute_adj(bool adj[NN][NN]) {
  uint32_t pool[4];
  uint32_t hc = 0x43b0d7e5u;
  auto hashmix = [&hc](uint32_t v) -> uint32_t {
    v ^= hc; hc *= 0x931e8875u; v *= hc; v ^= v >> 16; return v;
  };
  auto mix = [](uint32_t x, uint32_t y) -> uint32_t {
    uint32_t r = x * 0xca01f9ddu - y * 0x4973f715u; r ^= r >> 16; return r;
  };
  for (int i = 0; i < 4; i++) pool[i] = hashmix(0u);
  for (int s = 0; s < 4; s++)
    for (int d = 0; d < 4; d++)
      if (s != d) pool[d] = mix(pool[d], hashmix(pool[s]));
  uint32_t hb = 0x8b51f9ddu;
  uint32_t w[8];
  for (int k = 0; k < 8; k++) {
    uint32_t v = pool[k & 3];
    v ^= hb; hb *= 0x58f38dedu; v *= hb; v ^= v >> 16;
    w[k] = v;
  }
  uint64_t s64[4];
  for (int j = 0; j < 4; j++) s64[j] = (uint64_t)w[2 * j] | ((uint64_t)w[2 * j + 1] << 32);
  u128 initstate = ((u128)s64[0] << 64) | s64[1];
  u128 initseq   = ((u128)s64[2] << 64) | s64[3];
  const u128 MULT = ((u128)0x2360ED051FC65DA4ULL << 64) | 0x4385DF649FCCF645ULL;
  u128 state = 0;
  u128 inc = (initseq << 1) | 1;
  state = state * MULT + inc;
  state += initstate;
  state = state * MULT + inc;
  for (int i = 0; i < NN; i++)
    for (int j = 0; j < NN; j++) {
      state = state * MULT + inc;
      uint64_t hi = (uint64_t)(state >> 64), lo = (uint64_t)state;
      unsigned rot = (unsigned)(hi >> 58);
      uint64_t xr = hi ^ lo;
      uint64_t out = (xr >> rot) | (xr << ((64u - rot) & 63u));
      double dv = (double)(out >> 11) * (1.0 / 9007199254740992.0);
      adj[i][j] = (dv < 0.25);
    }
}

// ---------------- device ----------------
struct NodeDesc {
  uint8_t node, npred, slot, flags;
  uint8_t pred_slot[31];
  uint8_t pad;
};
struct GroupArg { int n; NodeDesc d[32]; };   // one launch per LEVEL
struct FinalArg { int nf; uint8_t slot[32]; };

__device__ __forceinline__ float bf2f_lo(unsigned int w) {
  union { unsigned int u; float f; } c; c.u = w << 16; return c.f;
}
__device__ __forceinline__ float bf2f_hi(unsigned int w) {
  union { unsigned int u; float f; } c; c.u = w & 0xFFFF0000u; return c.f;
}
__device__ __forceinline__ float bf2f(unsigned short h) {
  union { unsigned int u; float f; } c; c.u = ((unsigned int)h) << 16; return c.f;
}
__device__ __forceinline__ unsigned short f2bf(float f) {
  union { float f; unsigned int u; } c; c.f = f;
  unsigned int u = c.u + 0x7FFFu + ((c.u >> 16) & 1u);  // RNE
  return (unsigned short)(u >> 16);
}

// Workspace slots bf16 NHWC. Math fp32 except the pointwise, which is now
// MFMA bf16 (R18): R17's persistent-block kernel had MfmaUtil=0 and ~65% of
// its VALU work in a scalar 32x64x64 matmul. Per block-phase: 4 waves x
// (2 pos-tiles x 2 K-steps) mfma_f32_16x16x32_bf16; t-matrix in a dedicated
// bf16 LDS buffer with 16B-granule XOR swizzle. Fragment layouts (guide,
// HW-verified): A[m=lane&15][k=quad*8+j], B[n=lane&15][k=quad*8+j],
// D col=lane&15, row=quad*4+reg. Barriers cut 5 -> 3/node (wlds dbuf).
// Image b pinned to XCD b (R16); persistent 784-block grid (R17).
__global__ __launch_bounds__(256) void level_kernel(
    GroupArg g,
    const float* __restrict__ x,
    const float* __restrict__ dwall,
    const float* __restrict__ pwall,
    const float* __restrict__ gmall,
    const float* __restrict__ btall,
    const float* __restrict__ mnall,
    const float* __restrict__ vrall,
    const float* __restrict__ aggw,
    unsigned short* __restrict__ wsb)   // bf16 slots
{
  __shared__ float smem[3840];                          // halo [6r][10c][64ch] fp32
  __shared__ __align__(16) unsigned short pwb[2][4096]; // dbuf pw weights (bf16, swz)
  __shared__ __align__(16) unsigned short tbuf[2048];   // t[32 pos][64 c] (bf16, swz)
  __shared__ float wlds[2][32];                         // dbuf agg weights

  const int b = blockIdx.x & 7;       // image == XCD
  const int m = blockIdx.x >> 3;      // tile [0,98)
  const int t = threadIdx.x;
  const int ty = (m / 7) * 4;         // 14 y-tiles of 4 rows
  const int tx = (m % 7) * 8;         // 7 x-tiles of 8 cols

  // stage node g.d[kk]'s pw weights, bf16, granule-swizzled:
  // (o,c) -> o*64 + (((c>>3)^(o&7))<<3) | (c&7)
  auto stage = [&](int kk2, int bb) {
    const float* pwn = pwall + g.d[kk2].node * 4096;
    #pragma unroll
    for (int i = 0; i < 16; i++) {
      int gidx = t + 256 * i;
      int o = gidx >> 6, cc = gidx & 63;
      pwb[bb][o * 64 + ((((cc >> 3) ^ (o & 7)) << 3) | (cc & 7))] = f2bf(pwn[gidx]);
    }
  };

  stage(0, 0);

  for (int kk = 0; kk < g.n; kk++) {
    const NodeDesc nd = g.d[kk];
    const int node = nd.node;

    int dwc, pbase;
    if (nd.npred == 0) { dwc = t >> 2; pbase = (t & 3) * 8; }
    else               { dwc = t & 63; pbase = (t >> 6) * 8; }

    float* wl = wlds[kk & 1];
    if (t < nd.npred) {
      float wv = 1.f / (1.f + expf(-aggw[node * 32 + t]));
      wl[t] = (nd.npred == 1) ? 1.0f : wv;
    }
    __syncthreads();   // B1: wlds/pwb[kk&1] visible; tbuf + halo free (all MFMA done)

    const float* k9 = dwall + (node * 64 + dwc) * 9;
    float kk9[9];
    #pragma unroll
    for (int q = 0; q < 9; q++) kk9[q] = k9[q];

    float tv[8];

    if (nd.npred == 0) {
      // input node: depthwise stride-2 over relu(x), x NCHW [8][64][112][112]
      const float* xb = x + (size_t)(b * 64 + dwc) * 12544;
      #pragma unroll
      for (int jj = 0; jj < 8; jj++) {
        int p = pbase + jj;
        int oy = ty + (p >> 3), ox = tx + (p & 7);
        int iy0 = oy * 2 - 1, ix0 = ox * 2 - 1;
        float s = 0.f;
        #pragma unroll
        for (int dy = 0; dy < 3; dy++) {
          int iy = iy0 + dy;
          if ((unsigned)iy >= 112u) continue;
          const float* row = xb + iy * 112;
          #pragma unroll
          for (int dx = 0; dx < 3; dx++) {
            int ix = ix0 + dx;
            if ((unsigned)ix >= 112u) continue;
            s += fmaxf(row[ix], 0.f) * kk9[dy * 3 + dx];
          }
        }
        tv[jj] = s;
      }
      if (kk + 1 < g.n) stage(kk + 1, (kk + 1) & 1);
    } else {
      // aggregate + relu into fp32 NHWC halo (480 units of 8 ch = 16 B)
      const int np = nd.npred;
      float sa[2][8];
      int off[2];
      bool inb[2];
      #pragma unroll
      for (int u = 0; u < 2; u++) {
        int idx = t + u * 256;
        bool valid = (u == 0) || (t < 224);
        int pos = idx >> 3, q8 = idx & 7;
        int hy = pos / 10, hx = pos - hy * 10;
        int gy = ty + hy - 1, gx = tx + hx - 1;
        inb[u] = valid && ((unsigned)gy < 56u) && ((unsigned)gx < 56u);
        off[u] = ((b * 56 + gy) * 56 + gx) * 64 + q8 * 8;
        #pragma unroll
        for (int q = 0; q < 8; q++) sa[u][q] = 0.f;
      }
      for (int p0 = 0; p0 < np; p0 += 4) {
        uint4 v[4][2];
        #pragma unroll
        for (int pp = 0; pp < 4; pp++) {
          if (p0 + pp < np) {
            const unsigned short* pb = wsb + (size_t)nd.pred_slot[p0 + pp] * NODE_ELEMS;
            #pragma unroll
            for (int u = 0; u < 2; u++)
              if (inb[u]) v[pp][u] = *(const uint4*)(pb + off[u]);
          }
        }
        #pragma unroll
        for (int pp = 0; pp < 4; pp++) {
          if (p0 + pp < np) {
            float wv = wl[p0 + pp];
            #pragma unroll
            for (int u = 0; u < 2; u++) {
              if (inb[u]) {
                sa[u][0] = fmaf(wv, bf2f_lo(v[pp][u].x), sa[u][0]);
                sa[u][1] = fmaf(wv, bf2f_hi(v[pp][u].x), sa[u][1]);
                sa[u][2] = fmaf(wv, bf2f_lo(v[pp][u].y), sa[u][2]);
                sa[u][3] = fmaf(wv, bf2f_hi(v[pp][u].y), sa[u][3]);
                sa[u][4] = fmaf(wv, bf2f_lo(v[pp][u].z), sa[u][4]);
                sa[u][5] = fmaf(wv, bf2f_hi(v[pp][u].z), sa[u][5]);
                sa[u][6] = fmaf(wv, bf2f_lo(v[pp][u].w), sa[u][6]);
                sa[u][7] = fmaf(wv, bf2f_hi(v[pp][u].w), sa[u][7]);
              }
            }
          }
        }
      }
      #pragma unroll
      for (int u = 0; u < 2; u++) {
        int idx = t + u * 256;
        if ((u == 0) || (t < 224)) {
          float4 s0 = make_float4(fmaxf(sa[u][0], 0.f), fmaxf(sa[u][1], 0.f),
                                  fmaxf(sa[u][2], 0.f), fmaxf(sa[u][3], 0.f));
          float4 s1 = make_float4(fmaxf(sa[u][4], 0.f), fmaxf(sa[u][5], 0.f),
                                  fmaxf(sa[u][6], 0.f), fmaxf(sa[u][7], 0.f));
          *(float4*)&smem[idx * 8] = s0;
          *(float4*)&smem[idx * 8 + 4] = s1;
        }
      }
      if (kk + 1 < g.n) stage(kk + 1, (kk + 1) & 1);
      __syncthreads();   // B2: halo ready
      // depthwise 3x3 from NHWC halo: lane = channel -> conflict-free
      #pragma unroll
      for (int jj = 0; jj < 8; jj++) {
        int p = pbase + jj;
        int py = p >> 3, px = p & 7;
        const float* r0 = smem + (py * 10 + px) * 64 + dwc;
        tv[jj] = r0[0]    * kk9[0] + r0[64]   * kk9[1] + r0[128]  * kk9[2]
               + r0[640]  * kk9[3] + r0[704]  * kk9[4] + r0[768]  * kk9[5]
               + r0[1280] * kk9[6] + r0[1344] * kk9[7] + r0[1408] * kk9[8];
      }
    }

    // t matrix bf16, granule-swizzled: (p,c) -> p*64 + (((c>>3)^(p&7))<<3)|(c&7)
    #pragma unroll
    for (int jj = 0; jj < 8; jj++) {
      int p = pbase + jj;
      tbuf[p * 64 + ((((dwc >> 3) ^ (p & 7)) << 3) | (dwc & 7))] = f2bf(tv[jj]);
    }
    __syncthreads();   // B3: t ready; halo reads done

    // MFMA pointwise: D[32 pos][64 oc] = t x pw^T
    // wave w: mtile = w&1 (pos half), oc tiles {2*(w>>1), 2*(w>>1)+1}
    const int lane = t & 63;
    const int wave = t >> 6;
    const int mtile = wave & 1;
    const int npair = wave >> 1;
    const int lm = lane & 15;
    const int quad = lane >> 4;
    const unsigned short* pwc = pwb[kk & 1];

    bf16x8 afrag[2];
    #pragma unroll
    for (int ks = 0; ks < 2; ks++) {
      int pos = mtile * 16 + lm;
      int gg = ks * 4 + quad;
      afrag[ks] = *(const bf16x8*)&tbuf[pos * 64 + ((gg ^ (pos & 7)) << 3)];
    }
    f32x4 acc[2];
    #pragma unroll
    for (int nt = 0; nt < 2; nt++) {
      acc[nt] = (f32x4){0.f, 0.f, 0.f, 0.f};
      int oc = (npair * 2 + nt) * 16 + lm;
      #pragma unroll
      for (int ks = 0; ks < 2; ks++) {
        int gg = ks * 4 + quad;
        bf16x8 bfrag = *(const bf16x8*)&pwc[oc * 64 + ((gg ^ (oc & 7)) << 3)];
        acc[nt] = __builtin_amdgcn_mfma_f32_16x16x32_bf16(afrag[ks], bfrag, acc[nt], 0, 0, 0);
      }
    }

    // BN + bf16 slot store. D: col=lane&15 (oc), row=quad*4+reg (pos in tile)
    unsigned short* slotp = wsb + (size_t)nd.slot * NODE_ELEMS;
    #pragma unroll
    for (int nt = 0; nt < 2; nt++) {
      int oc = (npair * 2 + nt) * 16 + lm;
      int gi = node * 64 + oc;
      float inv = gmall[gi] / sqrtf(vrall[gi] + 1e-5f);
      float mn = mnall[gi], btv = btall[gi];
      #pragma unroll
      for (int r = 0; r < 4; r++) {
        int pos = mtile * 16 + quad * 4 + r;
        int gy = ty + (pos >> 3), gx = tx + (pos & 7);
        size_t base = (((size_t)(b * 56 + gy)) * 56 + gx) * 64 + oc;
        slotp[base] = f2bf((acc[nt][r] - mn) * inv + btv);
      }
    }
    // no trailing barrier: next iteration's B1 orders tbuf/pwb/halo reuse
  }
}

// Mean of FINAL bf16 slots (fp32 accumulate) -> NCHW d_out. Block per (b,y) row.
__global__ __launch_bounds__(256) void finalize_kernel(
    FinalArg fa, const unsigned short* __restrict__ wsb,
    float* __restrict__ out, float inv_nf)
{
  __shared__ float lds[57 * 64];
  int by = blockIdx.x;
  int b = by / 56, y = by - b * 56;
  size_t rbase = (((size_t)b * 56 + y) * 56) * 64;  // [x][c]
  for (int i = threadIdx.x; i < 3584; i += 256) {
    float s = 0.f;
    for (int f = 0; f < fa.nf; f++)
      s += bf2f(wsb[(size_t)fa.slot[f] * NODE_ELEMS + rbase + i]);
    int xx = i >> 6, c = i & 63;
    lds[c * 57 + xx] = s * inv_nf;
  }
  __syncthreads();
  float* dst = out + (size_t)b * 64 * 3136 + y * 56;
  for (int i = threadIdx.x; i < 3584; i += 256) {
    int c = i / 56, xx = i - c * 56;
    dst[(size_t)c * 3136 + xx] = lds[c * 57 + xx];
  }
}

// ---------------- launcher ----------------
extern "C" void kernel_launch(void* const* d_in, const int* in_sizes, int n_in,
                              void* d_out, int out_size, void* d_ws, size_t ws_size,
                              hipStream_t stream) {
  (void)in_sizes; (void)n_in; (void)ws_size; (void)out_size;
  const float* x     = (const float*)d_in[0];
  const float* dw    = (const float*)d_in[1];
  const float* pw    = (const float*)d_in[2];
  const float* gamma = (const float*)d_in[3];
  const float* beta  = (const float*)d_in[4];
  const float* mean  = (const float*)d_in[5];
  const float* var   = (const float*)d_in[6];
  const float* aggw  = (const float*)d_in[7];
  unsigned short* wsb = (unsigned short*)d_ws;
  float* out = (float*)d_out;

  bool adj[NN][NN];
  compute_adj(adj);

  int npred[NN], preds[NN][NN], nsucc[NN], ispan[NN], level[NN];
  for (int j = 0; j < NN; j++) {
    npred[j] = 0;
    for (int i = 0; i < j; i++) if (adj[i][j]) preds[j][npred[j]++] = i;
  }
  for (int i = 0; i < NN; i++) {
    nsucc[i] = 0; ispan[i] = NN;
    int mx = -1;
    for (int j = i + 1; j < NN; j++) if (adj[i][j]) { nsucc[i]++; mx = j; }
    if (nsucc[i] > 0) ispan[i] = mx;
  }
  int maxlev = 0;
  for (int j = 0; j < NN; j++) {
    int lv = 0;
    for (int p = 0; p < npred[j]; p++) {
      int cand = level[preds[j][p]] + 1;
      if (cand > lv) lv = cand;
    }
    level[j] = lv;
    if (lv > maxlev) maxlev = lv;
  }
  bool isfinal[NN]; int nf = 0;
  for (int i = 0; i < NN; i++) { isfinal[i] = (ispan[i] >= NN - 1); if (isfinal[i]) nf++; }
  int lastlvl[NN];
  for (int i = 0; i < NN; i++) {
    lastlvl[i] = -1;
    for (int j = i + 1; j < NN; j++) if (adj[i][j] && level[j] > lastlvl[i]) lastlvl[i] = level[j];
  }
  // slot allocation: every node gets a slot; FINAL slots never freed.
  int slot[NN]; bool used[NN];
  for (int s = 0; s < NN; s++) used[s] = false;
  for (int L = 0; L <= maxlev; L++) {
    for (int i = 0; i < NN; i++) {
      if (level[i] != L) continue;
      int s = 0; while (used[s]) s++;
      used[s] = true; slot[i] = s;
    }
    for (int i = 0; i < NN; i++)
      if (level[i] <= L && !isfinal[i] && lastlvl[i] == L)
        used[slot[i]] = false;
  }

  float inv_nf = 1.0f / (float)nf;

  for (int L = 0; L <= maxlev; L++) {
    GroupArg g; g.n = 0;
    for (int i = 0; i < NN; i++) {
      if (level[i] != L) continue;
      NodeDesc& nd = g.d[g.n++];
      nd.node = (uint8_t)i;
      nd.npred = (uint8_t)npred[i];
      nd.slot = (uint8_t)slot[i];
      nd.flags = 0;
      for (int p = 0; p < npred[i]; p++) nd.pred_slot[p] = (uint8_t)slot[preds[i][p]];
    }
    if (g.n > 0) {
      level_kernel<<<784, 256, 0, stream>>>(g, x, dw, pw, gamma, beta,
                                            mean, var, aggw, wsb);
    }
  }

  FinalArg fa; fa.nf = 0;
  for (int i = 0; i < NN; i++) if (isfinal[i]) fa.slot[fa.nf++] = (uint8_t)slot[i];
  finalize_kernel<<<448, 256, 0, stream>>>(fa, wsb, out, inv_nf);
}